// Round 4
// baseline (377.968 us; speedup 1.0000x reference)
//
#include <hip/hip_runtime.h>
#include <math.h>

#define EMB_D 64
#define N_EMB_K 1024
#define HW 4096        // 64*64
#define CHW 262144     // 64*4096
#define NPTS 65536     // 16*64*64
#define Q_OFF 1
#define PERP_OFF 4194305
#define ENC_OFF 4194306
#define FRAG_OFF 4096  // floats; W fragments live at ws+16KB (16B-aligned)

// ws layout (floats): [0..1023] c[k]=0.5*||W_k||^2 ; [1024..2047] hist (uint) ;
//                     [2048] loss accum ; [4096..69631] packed hi/lo bf16 B-frags (256 KB)

typedef __attribute__((ext_vector_type(8))) short short8;   // 8 bf16 = 4 VGPRs (MFMA A/B frag)
typedef __attribute__((ext_vector_type(4))) float float4v;  // MFMA C/D frag
typedef __attribute__((ext_vector_type(2))) float f2;       // native float2 (nontemporal-ok)

union S8 { short8 v; unsigned short u[8]; };

__device__ __forceinline__ unsigned short f2bf_rne(float f) {
    unsigned u = __builtin_bit_cast(unsigned, f);
    unsigned r = u + 0x7FFFu + ((u >> 16) & 1u);
    return (unsigned short)(r >> 16);
}
__device__ __forceinline__ float bf2f(unsigned short h) {
    unsigned u = ((unsigned)h) << 16;
    return __builtin_bit_cast(float, u);
}

// grid 32 x 256: pack W into pre-swizzled hi/lo B-fragments + c[k] + zero hist/loss.
// B-frag lane map (16x16x32): lane l holds B[k=(l>>4)*8+j][n=l&15]; chunk index
// c = t*4 + ks*2 + (hi?0:1), element = frag[c*64 + lane] (16B per lane -> coalesced).
__global__ __launch_bounds__(256) void vq_prep(const float* __restrict__ W,
                                               float* __restrict__ ws) {
    const int gid = blockIdx.x * 256 + threadIdx.x;   // 0..8191
    {
        const int code = gid >> 3;         // 0..1023
        const int seg  = gid & 7;          // which 8 d's
        const int d0   = seg << 3;
        const int t    = code >> 4;
        const int n    = code & 15;
        const int ks   = seg >> 2;
        const int lane = ((seg & 3) << 4) + n;
        const float4* wp = (const float4*)(W + (code << 6) + d0);
        const float4 f0 = wp[0], f1 = wp[1];
        const float vv[8] = {f0.x, f0.y, f0.z, f0.w, f1.x, f1.y, f1.z, f1.w};
        S8 hs, ls;
        #pragma unroll
        for (int j = 0; j < 8; ++j) {
            hs.u[j] = f2bf_rne(vv[j]);
            ls.u[j] = f2bf_rne(vv[j] - bf2f(hs.u[j]));
        }
        short8* frag = (short8*)(ws + FRAG_OFF);
        frag[(t * 4 + ks * 2 + 0) * 64 + lane] = hs.v;
        frag[(t * 4 + ks * 2 + 1) * 64 + lane] = ls.v;
    }
    if (gid < N_EMB_K) {
        const float* wk = W + (gid << 6);
        float s = 0.f;
        #pragma unroll
        for (int d = 0; d < EMB_D; ++d) s = fmaf(wk[d], wk[d], s);
        ws[gid] = 0.5f * s;
        ((unsigned int*)ws)[1024 + gid] = 0u;
        if (gid == 0) ws[2048] = 0.f;
    }
}

__global__ __launch_bounds__(256, 4) void vq_main(const float* __restrict__ in,
                                                  const float* __restrict__ W,
                                                  float* __restrict__ out,
                                                  float* __restrict__ ws) {
    __shared__ float x_lds[64 * 64];   // [d][p] fp32, 16 KB
    __shared__ int   s_bk[64];

    const int tid  = threadIdx.x;
    const int lane = tid & 63;
    const int wv   = tid >> 6;      // wave id, owns points wv*16..wv*16+15
    const int n16  = lane & 15;     // MFMA col (code-in-tile)
    const int quad = lane >> 4;

    const int blk = blockIdx.x;
    const int b   = blk >> 6;               // batch image
    const int hw0 = (blk & 63) * 64;        // 64 consecutive hw positions

    // ---- stage x tile (64 d x 64 points) into LDS, coalesced over hw ----
    {
        const float* src = in + (size_t)b * CHW + hw0;
        #pragma unroll
        for (int i = 0; i < 16; ++i) {
            const int d = wv * 16 + i;
            x_lds[d * 64 + lane] = src[d * HW + lane];
        }
    }
    __syncthreads();

    // ---- build A fragments (hi/lo split) for this wave's 16 points ----
    // A layout (16x16x32): m = lane&15, k = quad*8 + j  [m120-verified]
    short8 ah0, al0, ah1, al1;
    {
        const int p = wv * 16 + n16;
        S8 h0, l0, h1, l1;
        #pragma unroll
        for (int j = 0; j < 8; ++j) {
            const float v0 = x_lds[(quad * 8 + j) * 64 + p];
            const float v1 = x_lds[(32 + quad * 8 + j) * 64 + p];
            h0.u[j] = f2bf_rne(v0);
            l0.u[j] = f2bf_rne(v0 - bf2f(h0.u[j]));
            h1.u[j] = f2bf_rne(v1);
            l1.u[j] = f2bf_rne(v1 - bf2f(h1.u[j]));
        }
        ah0 = h0.v; al0 = l0.v; ah1 = h1.v; al1 = l1.v;
    }

    float bestv[4] = {-3.0e38f, -3.0e38f, -3.0e38f, -3.0e38f};
    int   bestk[4] = {0, 0, 0, 0};
    const float*  cvec = ws;
    const short8* frag = (const short8*)(ws + FRAG_OFF);
    f2* enc2 = (f2*)(out + ENC_OFF);           // 8B-aligned base
    const size_t zbase = (size_t)blk * 32768;  // block's 64 rows x 512 f2
    const f2 z2 = {0.f, 0.f};

    // ---- barrier-free k-loop: 64 tiles x (4 coalesced b128 loads + 6 MFMAs),
    //      encodings zero-fill interleaved so the 268 MB drains during compute ----
    #pragma unroll 4
    for (int t = 0; t < 64; ++t) {
        const int cb = (t << 2) * 64 + lane;
        const short8 bh0 = frag[cb];
        const short8 bl0 = frag[cb + 64];
        const short8 bh1 = frag[cb + 128];
        const short8 bl1 = frag[cb + 192];
        const float  cv  = cvec[(t << 4) + n16];
        __builtin_nontemporal_store(z2, enc2 + zbase + (size_t)(2 * t) * 256 + tid);
        __builtin_nontemporal_store(z2, enc2 + zbase + (size_t)(2 * t + 1) * 256 + tid);
        float4v acc = {-cv, -cv, -cv, -cv};    // score = x.w - 0.5||w||^2
        acc = __builtin_amdgcn_mfma_f32_16x16x32_bf16(ah0, bh0, acc, 0, 0, 0);
        acc = __builtin_amdgcn_mfma_f32_16x16x32_bf16(ah1, bh1, acc, 0, 0, 0);
        acc = __builtin_amdgcn_mfma_f32_16x16x32_bf16(al0, bh0, acc, 0, 0, 0);
        acc = __builtin_amdgcn_mfma_f32_16x16x32_bf16(al1, bh1, acc, 0, 0, 0);
        acc = __builtin_amdgcn_mfma_f32_16x16x32_bf16(ah0, bl0, acc, 0, 0, 0);
        acc = __builtin_amdgcn_mfma_f32_16x16x32_bf16(ah1, bl1, acc, 0, 0, 0);
        const int code = (t << 4) + n16;
        #pragma unroll
        for (int r = 0; r < 4; ++r) {
            if (acc[r] > bestv[r]) { bestv[r] = acc[r]; bestk[r] = code; }  // strict > => lowest k
        }
    }

    // ---- cross-lane argmax reduce within each 16-lane col group ----
    #pragma unroll
    for (int off = 1; off < 16; off <<= 1) {
        #pragma unroll
        for (int r = 0; r < 4; ++r) {
            const float ov = __shfl_xor(bestv[r], off, 64);
            const int   oi = __shfl_xor(bestk[r], off, 64);
            if (ov > bestv[r] || (ov == bestv[r] && oi < bestk[r])) {
                bestv[r] = ov; bestk[r] = oi;
            }
        }
    }
    if (n16 == 0) {
        #pragma unroll
        for (int r = 0; r < 4; ++r) s_bk[wv * 16 + quad * 4 + r] = bestk[r];
    }
    __syncthreads();   // also drains the zero-fill stores (vmcnt(0) before s_barrier)

    // ---- scatter the ones + histogram ----
    if (tid < 64) {
        const int bk = s_bk[tid];
        atomicAdd((unsigned int*)ws + 1024 + bk, 1u);
        out[ENC_OFF + ((size_t)(blk * 64 + tid) << 10) + bk] = 1.0f;
    }

    // ---- quantized_st (NCHW) + exact fp32 loss from winner rows ----
    {
        float* quant = out + Q_OFF;
        const int p  = lane;
        const int bk = s_bk[p];
        const float* wrow = W + (bk << 6);
        float lsum = 0.f;
        #pragma unroll
        for (int dd = 0; dd < 16; ++dd) {
            const int d = wv * 16 + dd;
            const float xv  = x_lds[d * 64 + p];
            const float qv  = wrow[d];
            const float diff = qv - xv;
            lsum = fmaf(diff, diff, lsum);
            __builtin_nontemporal_store(xv + diff,
                quant + (size_t)b * CHW + d * HW + hw0 + p);
        }
        #pragma unroll
        for (int off = 1; off < 64; off <<= 1) lsum += __shfl_xor(lsum, off, 64);
        if (lane == 0) atomicAdd(ws + 2048, lsum);
    }
}

__global__ __launch_bounds__(256) void vq_final(const float* __restrict__ ws,
                                                float* __restrict__ out) {
    __shared__ float red[256];
    const int tid = threadIdx.x;
    const unsigned int* hist = (const unsigned int*)ws + 1024;
    float local = 0.f;
    #pragma unroll
    for (int j = 0; j < 4; ++j) {
        const unsigned int cnt = hist[tid + j * 256];
        const float pr = (float)cnt * (1.0f / 65536.0f);
        local += pr * logf(pr + 1e-10f);
    }
    red[tid] = local;
    __syncthreads();
    for (int off = 128; off > 0; off >>= 1) {
        if (tid < off) red[tid] += red[tid + off];
        __syncthreads();
    }
    if (tid == 0) {
        out[PERP_OFF] = expf(-red[0]);
        out[0] = 1.25f * ws[2048] * (1.0f / 4194304.0f);
    }
}

extern "C" void kernel_launch(void* const* d_in, const int* in_sizes, int n_in,
                              void* d_out, int out_size, void* d_ws, size_t ws_size,
                              hipStream_t stream) {
    const float* in = (const float*)d_in[0];   // (16,64,64,64) fp32 NCHW
    const float* W  = (const float*)d_in[1];   // (1024,64) fp32
    float* out = (float*)d_out;                // [loss | quant(4194304) | perp | enc(67108864)]
    float* ws  = (float*)d_ws;

    vq_prep<<<32, 256, 0, stream>>>(W, ws);
    vq_main<<<NPTS / 64, 256, 0, stream>>>(in, W, out, ws);
    vq_final<<<1, 256, 0, stream>>>(ws, out);
}